// Round 11
// baseline (197.230 us; speedup 1.0000x reference)
//
#include <hip/hip_runtime.h>
#include <hip/hip_bf16.h>

// T=64, N=20000, F=8, H=32. edge_index/edge_weight dead (K=1 ChebConv).
// R20 = R18 schedule + R19's packed-uint2 exchange (kept) - R19's own/peer
// MFMA split (REVERTED: +6 MFMAs lengthened every chain; MfmaUtil 11->17
// with no wall gain) + TWO GRU STREAMS PER WAVE.
// Model (R17-R19 counters): wall 3190cy/step, issue 650cy/wave-step,
// VALUBusy pinned ~50% -- stalls (LDS latency, MFMA->VALU, trans chains,
// barrier skew) that 1.2-2.4 waves/SIMD cannot hide. More waves is proven
// loss (R15: halving nodes/wave doubles total issue). The lever is ILP at
// CONSTANT total issue: each wave owns dim-tile Rown of TWO independent
// 16-node groups. Weights shared (same tile -> zero extra weight VGPRs);
// the sibling stream fills every stall window. Block = 32 nodes / 2 waves,
// grid 625, all resident (LDS 39.7KB -> 4 blocks/CU >= 2.44 needed).
// Numerics bit-identical per stream to R18/R19 -> absmax 0.009155.
#define T_STEPS 64
#define N_NODES 20000
#define F_IN    8
#define H_DIM   32
#define NEG_SLOPE 0.01f
#define WS_STRIDE 32   // floats; one 128B cacheline per t
#define LOG2E 1.44269504f

typedef __attribute__((ext_vector_type(8))) short bf16x8;
typedef __attribute__((ext_vector_type(4))) float f32x4;

#define MFMA(a, b, c) __builtin_amdgcn_mfma_f32_16x16x32_bf16((a), (b), (c), 0, 0, 0)

// ---------- RNE helpers (cold path: weight/frag setup only) ----------
__device__ __forceinline__ unsigned short f2bf(float f) {
    unsigned u = __float_as_uint(f);
    u += 0x7FFFu + ((u >> 16) & 1u);          // RNE
    return (unsigned short)(u >> 16);
}
__device__ __forceinline__ float bf2f(unsigned short s) {
    return __uint_as_float(((unsigned)s) << 16);
}
__device__ __forceinline__ void split_pack8_rne(const float* v, bf16x8& hi, bf16x8& lo) {
    union { unsigned u[4]; bf16x8 v8; } H, L;
#pragma unroll
    for (int p = 0; p < 4; ++p) {
        float a = v[2*p], b = v[2*p+1];
        unsigned short ha = f2bf(a), hb = f2bf(b);
        unsigned short la = f2bf(a - bf2f(ha)), lb = f2bf(b - bf2f(hb));
        H.u[p] = (unsigned)ha | ((unsigned)hb << 16);
        L.u[p] = (unsigned)la | ((unsigned)lb << 16);
    }
    hi = H.v8; lo = L.v8;
}

// ---------- hot-path pack: HW v_cvt_pk_bf16_f32 via standard casts ----------
__device__ __forceinline__ unsigned cvtpk(float a, float b) {
    union { __hip_bfloat162 h; unsigned u; } U;
    U.h = __float22bfloat162_rn(float2{a, b});   // lo16 = bf(a), hi16 = bf(b)
    return U.u;
}

// Wave-relative K-permutation: k-slot (q, j) -> h-dim
//   j<4  -> Rown + 4q + j      (own dims; B-frag words u[0],u[1])
//   j>=4 -> Roth + 4q + (j-4)  (peer dims; B-frag words u[2],u[3])
// Applied to BOTH A and B frags, so each gate's C-layout == next B layout,
// and the peer's packed own-half IS our u[2],u[3].

// A-frag of W^T for output tile Rout, K in wave-relative sigma order,
// pre-scaled (log2e folds the exp base change into static data).
__device__ __forceinline__ void load_wfragW(const float* __restrict__ W, int c, int q,
                                            int Rout, int Rown, int Roth, float scale,
                                            bf16x8& hi, bf16x8& lo) {
    float v[8];
#pragma unroll
    for (int j = 0; j < 8; ++j) {
        int dim = (j < 4) ? (Rown + 4*q + j) : (Roth + 4*q + (j - 4));
        v[j] = W[dim * H_DIM + (Rout + c)] * scale;
    }
    split_pack8_rne(v, hi, lo);
}

// Combined x-weight + bias A-frag for tile Rout (K-slot plan, k = 8q+j):
//   q=0: W_hi[j]   q=1: W_lo[j]   q=2: 0   q=3: j==0 bias_hi, j==1 bias_lo
// pairs with x B-frag (q0: x_rne, q1: x_rne, q2: 0, q3: {1,1,0..}) ->
//   x*(W_hi+W_lo) + bias  (weight full precision, x single RNE bf16).
__device__ __forceinline__ bf16x8 load_xwfragW(const float* __restrict__ Wx,
                                               const float* __restrict__ bx,
                                               const float* __restrict__ bh,
                                               int c, int q, int Rout, float scale) {
    union { unsigned short s[8]; bf16x8 v8; } U;
#pragma unroll
    for (int j = 0; j < 8; ++j) U.s[j] = 0;
    if (q == 0) {
#pragma unroll
        for (int j = 0; j < 8; ++j) U.s[j] = f2bf(Wx[j * H_DIM + Rout + c] * scale);
    } else if (q == 1) {
#pragma unroll
        for (int j = 0; j < 8; ++j) {
            float w0 = Wx[j * H_DIM + Rout + c] * scale;
            unsigned short h = f2bf(w0);
            U.s[j] = f2bf(w0 - bf2f(h));
        }
    } else if (q == 3) {
        float b = (bx[Rout + c] + bh[Rout + c]) * scale;
        unsigned short h = f2bf(b);
        U.s[0] = h;
        U.s[1] = f2bf(b - bf2f(h));
    }
    return U.v8;
}

// x B-frag: q0/q1 -> x (RNE bf16), q2 -> 0, q3 -> {1.0,1.0,0,...}
__device__ __forceinline__ bf16x8 build_xbfrag2(const float* v, int q) {
    union { unsigned u[4]; bf16x8 v8; } U;
#pragma unroll
    for (int p = 0; p < 4; ++p) {
        unsigned val = cvtpk(v[2*p], v[2*p+1]);
        if (q == 2) val = 0u;
        if (q == 3) val = (p == 0) ? 0x3F803F80u : 0u;   // 1.0,1.0 at k=24,25
        U.u[p] = val;
    }
    return U.v8;
}

// full B-frag from packed own + packed peer halves
__device__ __forceinline__ bf16x8 frag4(unsigned o01, unsigned o23,
                                        unsigned p01, unsigned p23) {
    union { unsigned u[4]; bf16x8 v8; } U;
    U.u[0] = o01; U.u[1] = o23; U.u[2] = p01; U.u[3] = p23;
    return U.v8;
}

// activations on PRE-SCALED pre-activations (x' = x*log2e, y' = y*2log2e):
// sigmoid(x) = rcp(1 + 2^(-x')), tanh(y) = 1 - 2*rcp(1 + 2^(y'))
__device__ __forceinline__ float sigmoid2_f(float xp) {
    return __builtin_amdgcn_rcpf(1.0f + __builtin_amdgcn_exp2f(-xp));
}
__device__ __forceinline__ float tanh2_f(float yp) {
    return 1.0f - 2.0f * __builtin_amdgcn_rcpf(1.0f + __builtin_amdgcn_exp2f(yp));
}
__device__ __forceinline__ float leaky_f(float x) {
    return fmaxf(x, NEG_SLOPE * x);   // == LeakyReLU for 0<slope<1
}

__global__ void final_kernel(const float* __restrict__ ws, const float* __restrict__ b2,
                             float* __restrict__ out) {
    int t = threadIdx.x;
    if (t < T_STEPS) out[t] = ws[t * WS_STRIDE] + b2[0];
}

__global__ __launch_bounds__(128, 2) void rgcn_mfma_kernel(
    const float* __restrict__ x,    // [T,N,F]
    const float* __restrict__ h0,   // [N,H]
    const float* __restrict__ Wxz, const float* __restrict__ bxz,
    const float* __restrict__ Whz, const float* __restrict__ bhz,
    const float* __restrict__ Wxr, const float* __restrict__ bxr,
    const float* __restrict__ Whr, const float* __restrict__ bhr,
    const float* __restrict__ Wxh, const float* __restrict__ bxh,
    const float* __restrict__ Whh, const float* __restrict__ bhh,
    const float* __restrict__ W1,  const float* __restrict__ b1,
    const float* __restrict__ W2,
    float* __restrict__ ws,         // [T*WS_STRIDE] accumulators (poison ~ -3e-13, negligible)
    float* __restrict__ out)        // [T] then [N,H]
{
    const int tid  = threadIdx.x;
    const int w    = tid >> 6;       // wave id: owns dim-tile Rown (both streams)
    const int l    = tid & 63;
    const int c    = l & 15;
    const int q    = l >> 4;
    const int base = blockIdx.x * 32;        // 32 nodes per block
    const int nodeA = base + c;              // stream A: nodes base..base+15
    const int nodeB = base + 16 + c;         // stream B: nodes base+16..base+31
    const int Rown = 16 * w;
    const int Roth = 16 - Rown;

    // PACKED bf16 exchanges: [parity][wave][stream][q][c]
    __shared__ __align__(8) uint2 hxbuf[2][2][2][4][16];
    __shared__ __align__(8) uint2 rhbuf[2][2][4][16];
    // head partials as bf16: stream A at col tid, stream B at col 131+tid
    __shared__ unsigned short pbuf16[T_STEPS][262];

    // ---- static A-frags (shared by BOTH streams): 9 frags = 36 VGPR ----
    bf16x8 WHrOh, WHrOl, WHzh, WHzl, WHhh, WHhl;
    load_wfragW(Whr, c, q, Rown, Rown, Roth, LOG2E,        WHrOh, WHrOl);
    load_wfragW(Whz, c, q, Rown, Rown, Roth, LOG2E,        WHzh,  WHzl);
    load_wfragW(Whh, c, q, Rown, Rown, Roth, 2.0f * LOG2E, WHhh,  WHhl);
    bf16x8 WXr = load_xwfragW(Wxr, bxr, bhr, c, q, Rown, LOG2E);
    bf16x8 WXz = load_xwfragW(Wxz, bxz, bhz, c, q, Rown, LOG2E);
    bf16x8 WXh = load_xwfragW(Wxh, bxh, bhh, c, q, Rown, 2.0f * LOG2E);

    // head constants
    float w1v[4];
#pragma unroll
    for (int i = 0; i < 4; ++i) w1v[i] = W1[Rown + 4*q + i];
    const float b1s = b1[0];
    const float w2A = W2[nodeA];
    const float w2B = W2[nodeB];

    // per-stream h state: own 4 dims (f32) + pre-packed own bf16 pair
    float hvA[4], hvB[4];
    unsigned ownA01, ownA23, ownB01, ownB23;
    {
        float4 hA = ((const float4*)(h0 + (size_t)nodeA * H_DIM + Rown))[q];
        hvA[0] = hA.x; hvA[1] = hA.y; hvA[2] = hA.z; hvA[3] = hA.w;
        ownA01 = cvtpk(hvA[0], hvA[1]);
        ownA23 = cvtpk(hvA[2], hvA[3]);
        hxbuf[0][w][0][q][c] = uint2{ownA01, ownA23};
        float4 hB = ((const float4*)(h0 + (size_t)nodeB * H_DIM + Rown))[q];
        hvB[0] = hB.x; hvB[1] = hB.y; hvB[2] = hB.z; hvB[3] = hB.w;
        ownB01 = cvtpk(hvB[0], hvB[1]);
        ownB23 = cvtpk(hvB[2], hvB[3]);
        hxbuf[0][w][1][q][c] = uint2{ownB01, ownB23};
    }

    const f32x4 zero4 = {0.0f, 0.0f, 0.0f, 0.0f};

    // x(0) frags -> hoisted x-part accumulators; prefetch x(1), both streams
    f32x4 axrA, axzA, axhA, axrB, axzB, axhB;
    {
        const float4* xpA = (const float4*)(x + (size_t)nodeA * F_IN);
        float4 a0 = xpA[0], a1 = xpA[1];
        float va[8] = {a0.x, a0.y, a0.z, a0.w, a1.x, a1.y, a1.z, a1.w};
        bf16x8 fxA = build_xbfrag2(va, q);
        axrA = MFMA(WXr, fxA, zero4);
        axzA = MFMA(WXz, fxA, zero4);
        axhA = MFMA(WXh, fxA, zero4);
        const float4* xpB = (const float4*)(x + (size_t)nodeB * F_IN);
        float4 b0 = xpB[0], b1v4 = xpB[1];
        float vb[8] = {b0.x, b0.y, b0.z, b0.w, b1v4.x, b1v4.y, b1v4.z, b1v4.w};
        bf16x8 fxB = build_xbfrag2(vb, q);
        axrB = MFMA(WXr, fxB, zero4);
        axzB = MFMA(WXz, fxB, zero4);
        axhB = MFMA(WXh, fxB, zero4);
    }
    float4 cxA0, cxA1, cxB0, cxB1;   // x(t+1)
    {
        const float4* xpA = (const float4*)(x + (size_t)(N_NODES * F_IN)
                                              + (size_t)nodeA * F_IN);
        cxA0 = xpA[0]; cxA1 = xpA[1];
        const float4* xpB = (const float4*)(x + (size_t)(N_NODES * F_IN)
                                              + (size_t)nodeB * F_IN);
        cxB0 = xpB[0]; cxB1 = xpB[1];
    }

    __syncthreads();     // hxbuf parity 0 visible

#pragma unroll 1
    for (int t = 0; t < T_STEPS; ++t) {
        const int rp = t & 1;          // read parity; write parity = 1-rp

        // issue both peer packed h reads back-to-back
        uint2 ohpA = hxbuf[rp][1 - w][0][q][c];
        uint2 ohpB = hxbuf[rp][1 - w][1][q][c];

        // issue x(t+2) loads now; consumed ~1.5 steps later
        int tt = (t + 2 < T_STEPS) ? (t + 2) : (T_STEPS - 1);
        const float4* xpA = (const float4*)(x + (size_t)tt * (N_NODES * F_IN)
                                              + (size_t)nodeA * F_IN);
        float4 nxA0 = xpA[0], nxA1 = xpA[1];
        const float4* xpB = (const float4*)(x + (size_t)tt * (N_NODES * F_IN)
                                              + (size_t)nodeB * F_IN);
        float4 nxB0 = xpB[0], nxB1 = xpB[1];

        // r + z MFMA chains, streams interleaved (independent chains fill
        // each other's LDS/MFMA latency)
        bf16x8 fhA = frag4(ownA01, ownA23, ohpA.x, ohpA.y);
        bf16x8 fhB = frag4(ownB01, ownB23, ohpB.x, ohpB.y);
        f32x4 arAa = MFMA(WHrOh, fhA, axrA);
        f32x4 arBa = MFMA(WHrOh, fhB, axrB);
        f32x4 arAb = MFMA(WHrOl, fhA, zero4);
        f32x4 arBb = MFMA(WHrOl, fhB, zero4);
        f32x4 azA  = MFMA(WHzh,  fhA, axzA);
        f32x4 azB  = MFMA(WHzh,  fhB, axzB);
        azA        = MFMA(WHzl,  fhA, azA);
        azB        = MFMA(WHzl,  fhB, azB);

        f32x4 arA = arAa + arAb;
        f32x4 arB = arBa + arBb;

        // r gate + r*h, pack once, publish packed (both streams)
        float rhA[4], rhB[4];
#pragma unroll
        for (int i = 0; i < 4; ++i) {
            rhA[i] = sigmoid2_f(arA[i]) * hvA[i];
            rhB[i] = sigmoid2_f(arB[i]) * hvB[i];
        }
        unsigned rhA01 = cvtpk(rhA[0], rhA[1]);
        unsigned rhA23 = cvtpk(rhA[2], rhA[3]);
        unsigned rhB01 = cvtpk(rhB[0], rhB[1]);
        unsigned rhB23 = cvtpk(rhB[2], rhB[3]);
        rhbuf[w][0][q][c] = uint2{rhA01, rhA23};
        rhbuf[w][1][q][c] = uint2{rhB01, rhB23};

        // next-x frag builds fill the pre-barrier gap
        float nvA[8] = {cxA0.x, cxA0.y, cxA0.z, cxA0.w, cxA1.x, cxA1.y, cxA1.z, cxA1.w};
        bf16x8 fxnA = build_xbfrag2(nvA, q);
        float nvB[8] = {cxB0.x, cxB0.y, cxB0.z, cxB0.w, cxB1.x, cxB1.y, cxB1.z, cxB1.w};
        bf16x8 fxnB = build_xbfrag2(nvB, q);

        __syncthreads();   // barrier 1: rhbuf ready

        // peer packed rh reads; latency filled by nx-MFMAs + z sigmoids
        uint2 orhA = rhbuf[1 - w][0][q][c];
        uint2 orhB = rhbuf[1 - w][1][q][c];
        f32x4 nxrA = MFMA(WXr, fxnA, zero4);
        f32x4 nxrB = MFMA(WXr, fxnB, zero4);
        f32x4 nxzA = MFMA(WXz, fxnA, zero4);
        f32x4 nxzB = MFMA(WXz, fxnB, zero4);
        f32x4 nxhA = MFMA(WXh, fxnA, zero4);
        f32x4 nxhB = MFMA(WXh, fxnB, zero4);

        float zvA[4], zvB[4];
#pragma unroll
        for (int i = 0; i < 4; ++i) {
            zvA[i] = sigmoid2_f(azA[i]);
            zvB[i] = sigmoid2_f(azB[i]);
        }

        bf16x8 frA = frag4(rhA01, rhA23, orhA.x, orhA.y);
        bf16x8 frB = frag4(rhB01, rhB23, orhB.x, orhB.y);
        f32x4 ahAa = MFMA(WHhh, frA, axhA);
        f32x4 ahBa = MFMA(WHhh, frB, axhB);
        f32x4 ahAb = MFMA(WHhl, frA, zero4);
        f32x4 ahBb = MFMA(WHhl, frB, zero4);
        f32x4 ahA = ahAa + ahAb;
        f32x4 ahB = ahBa + ahBb;

        // tanh, blend (th + z*(hv-th)), head partials, both streams
        float pnewA = 0.0f, pnewB = 0.0f;
#pragma unroll
        for (int i = 0; i < 4; ++i) {
            float thA = tanh2_f(ahA[i]);
            float hnA = thA + zvA[i] * (hvA[i] - thA);
            hvA[i] = hnA;
            pnewA = fmaf(leaky_f(hnA), w1v[i], pnewA);
            float thB = tanh2_f(ahB[i]);
            float hnB = thB + zvB[i] * (hvB[i] - thB);
            hvB[i] = hnB;
            pnewB = fmaf(leaky_f(hnB), w1v[i], pnewB);
        }
        pbuf16[t][tid]       = (unsigned short)cvtpk(pnewA, pnewA);
        pbuf16[t][131 + tid] = (unsigned short)cvtpk(pnewB, pnewB);

        // pack h(t+1) once; publish packed (both streams)
        ownA01 = cvtpk(hvA[0], hvA[1]);
        ownA23 = cvtpk(hvA[2], hvA[3]);
        hxbuf[1 - rp][w][0][q][c] = uint2{ownA01, ownA23};
        ownB01 = cvtpk(hvB[0], hvB[1]);
        ownB23 = cvtpk(hvB[2], hvB[3]);
        hxbuf[1 - rp][w][1][q][c] = uint2{ownB01, ownB23};

        axrA = nxrA; axzA = nxzA; axhA = nxhA;
        axrB = nxrB; axzB = nxzB; axhB = nxhB;
        cxA0 = nxA0; cxA1 = nxA1; cxB0 = nxB0; cxB1 = nxB1;

        __syncthreads();   // barrier 2: h(t+1) exchange + rhbuf reuse fence
    }

    // ---- post-loop head reduction: each wave handles 32 t's ----
    // lane (c,q), rep: t = w*32 + rep*4 + q; per t sum 8 partials per stream
#pragma unroll
    for (int rep = 0; rep < 8; ++rep) {
        int t = w * 32 + rep * 4 + q;
        float sA = 0.0f, sB = 0.0f;
#pragma unroll
        for (int g = 0; g < 8; ++g) {
            sA += bf2f(pbuf16[t][g * 16 + c]);
            sB += bf2f(pbuf16[t][131 + g * 16 + c]);
        }
        float a2 = fmaf(leaky_f(sA + b1s), w2A, leaky_f(sB + b1s) * w2B);
        a2 += __shfl_xor(a2, 1); a2 += __shfl_xor(a2, 2);
        a2 += __shfl_xor(a2, 4); a2 += __shfl_xor(a2, 8);
        if (c == 0) atomicAdd(&ws[t * WS_STRIDE], a2);
    }

    // h_fin: each wave stores its dim-tile for both streams
    *(float4*)(out + T_STEPS + (size_t)nodeA * H_DIM + Rown + 4*q) =
        (float4){hvA[0], hvA[1], hvA[2], hvA[3]};
    *(float4*)(out + T_STEPS + (size_t)nodeB * H_DIM + Rown + 4*q) =
        (float4){hvB[0], hvB[1], hvB[2], hvB[3]};
}

extern "C" void kernel_launch(void* const* d_in, const int* in_sizes, int n_in,
                              void* d_out, int out_size, void* d_ws, size_t ws_size,
                              hipStream_t stream) {
    const float* x    = (const float*)d_in[0];
    // d_in[1] edge_index (int64), d_in[2] edge_weight: dead for K=1 ChebConv
    const float* h0   = (const float*)d_in[3];
    const float* Wxz  = (const float*)d_in[4];
    const float* bxz  = (const float*)d_in[5];
    const float* Whz  = (const float*)d_in[6];
    const float* bhz  = (const float*)d_in[7];
    const float* Wxr  = (const float*)d_in[8];
    const float* bxr  = (const float*)d_in[9];
    const float* Whr  = (const float*)d_in[10];
    const float* bhr  = (const float*)d_in[11];
    const float* Wxh  = (const float*)d_in[12];
    const float* bxh  = (const float*)d_in[13];
    const float* Whh  = (const float*)d_in[14];
    const float* bhh  = (const float*)d_in[15];
    const float* W1   = (const float*)d_in[16];
    const float* b1   = (const float*)d_in[17];
    const float* W2   = (const float*)d_in[18];
    const float* b2   = (const float*)d_in[19];
    float* out = (float*)d_out;
    float* ws  = (float*)d_ws;

    const int grid = N_NODES / 32;  // 625 blocks x 2 waves; 2 streams per wave
    rgcn_mfma_kernel<<<grid, 128, 0, stream>>>(
        x, h0, Wxz, bxz, Whz, bhz, Wxr, bxr, Whr, bhr,
        Wxh, bxh, Whh, bhh, W1, b1, W2, ws, out);

    final_kernel<<<1, 64, 0, stream>>>(ws, b2, out);
}

// Round 12
// 189.814 us; speedup vs baseline: 1.0391x; 1.0391x over previous
//
#include <hip/hip_runtime.h>
#include <hip/hip_bf16.h>

// T=64, N=20000, F=8, H=32. edge_index/edge_weight dead (K=1 ChebConv).
// R21: 4-WAVE dim-split -> 5000 waves (4.88/SIMD). Evidence: R18 best at
// 85us (VALUBusy 50%, issue 655cy/wave-step, stall ~1000cy); both ILP
// attempts (R19 MFMA-split, R20 2-stream) LOST -> the lever is TLP at
// constant total work. Each wave owns 8 dims (2/lane): sigma k-slot
// (q,j) -> dim 8*(j>>1)+2q+(j&1); wave w's dims sit at C-rows 4q+{0,1}
// (A-rows (c&3)<2, rest zero). Wave w's packed own-pair IS word w of
// EVERY wave's h B-frag: exchange = 1 uint write + 1 uint4 read, the
// ds_read result is the MFMA operand directly (zero unpack).
// Per-wave/step: 9 MFMAs (half-wasted; pipe was 17% -> absorbs 2x),
// 12 trans (was 24), ~300cy issue. Head: 2-dim partial + 2 shfl q-reduce
// + 1 bf16 write -> pbuf 8.7KB; LDS ~12KB; launch_bounds(256,5) -> 5
// blocks/CU -> all 1250 blocks resident in ONE round.
// Numerics: same per-dim products/association as R18 -> absmax ~0.009.
#define T_STEPS 64
#define N_NODES 20000
#define F_IN    8
#define H_DIM   32
#define NEG_SLOPE 0.01f
#define WS_STRIDE 32   // floats; one 128B cacheline per t
#define LOG2E 1.44269504f

typedef __attribute__((ext_vector_type(8))) short bf16x8;
typedef __attribute__((ext_vector_type(4))) float f32x4;

#define MFMA(a, b, c) __builtin_amdgcn_mfma_f32_16x16x32_bf16((a), (b), (c), 0, 0, 0)

// ---------- RNE helpers (cold path) ----------
__device__ __forceinline__ unsigned short f2bf(float f) {
    unsigned u = __float_as_uint(f);
    u += 0x7FFFu + ((u >> 16) & 1u);          // RNE
    return (unsigned short)(u >> 16);
}
__device__ __forceinline__ float bf2f(unsigned short s) {
    return __uint_as_float(((unsigned)s) << 16);
}
__device__ __forceinline__ void split_pack8_rne(const float* v, bf16x8& hi, bf16x8& lo) {
    union { unsigned u[4]; bf16x8 v8; } H, L;
#pragma unroll
    for (int p = 0; p < 4; ++p) {
        float a = v[2*p], b = v[2*p+1];
        unsigned short ha = f2bf(a), hb = f2bf(b);
        unsigned short la = f2bf(a - bf2f(ha)), lb = f2bf(b - bf2f(hb));
        H.u[p] = (unsigned)ha | ((unsigned)hb << 16);
        L.u[p] = (unsigned)la | ((unsigned)lb << 16);
    }
    hi = H.v8; lo = L.v8;
}

// ---------- hot-path pack: HW v_cvt_pk_bf16_f32 ----------
__device__ __forceinline__ unsigned cvtpk(float a, float b) {
    union { __hip_bfloat162 h; unsigned u; } U;
    U.h = __float22bfloat162_rn(float2{a, b});   // lo16 = bf(a), hi16 = bf(b)
    return U.u;
}

// sigma for the 4-way split: k-slot (q, j) -> h-dim. Word j>>1 of the
// B-frag holds wave (j>>1)'s pair for lane-group q.
__device__ __forceinline__ int sigma8(int q, int j) {
    return 8 * (j >> 1) + 2 * q + (j & 1);
}
// A-row c of wave w's output tile -> global output dim (valid iff (c&3)<2)
__device__ __forceinline__ int dim_for_row(int w, int c) {
    return 8 * w + 2 * (c >> 2) + (c & 3);
}

// A-frag of W^T for wave w's 8-dim tile. Rows with (c&3)>=2 are zero.
__device__ __forceinline__ void load_wfragW8(const float* __restrict__ W, int c, int q,
                                             int w, float scale, bf16x8& hi, bf16x8& lo) {
    const bool valid = (c & 3) < 2;
    const int  col   = dim_for_row(w, c);
    float v[8];
#pragma unroll
    for (int j = 0; j < 8; ++j)
        v[j] = valid ? W[sigma8(q, j) * H_DIM + col] * scale : 0.0f;
    split_pack8_rne(v, hi, lo);
}

// Combined x-weight + bias A-frag (K-plan: q0 W_hi, q1 W_lo, q2 0,
// q3 j=0/1 bias hi/lo; pairs with x B-frag q0/q1 = x, q3 = {1,1,0..}).
__device__ __forceinline__ bf16x8 load_xwfragW8(const float* __restrict__ Wx,
                                                const float* __restrict__ bx,
                                                const float* __restrict__ bh,
                                                int c, int q, int w, float scale) {
    const bool valid = (c & 3) < 2;
    const int  col   = dim_for_row(w, c);
    union { unsigned short s[8]; bf16x8 v8; } U;
#pragma unroll
    for (int j = 0; j < 8; ++j) U.s[j] = 0;
    if (valid) {
        if (q == 0) {
#pragma unroll
            for (int j = 0; j < 8; ++j) U.s[j] = f2bf(Wx[j * H_DIM + col] * scale);
        } else if (q == 1) {
#pragma unroll
            for (int j = 0; j < 8; ++j) {
                float w0 = Wx[j * H_DIM + col] * scale;
                unsigned short h = f2bf(w0);
                U.s[j] = f2bf(w0 - bf2f(h));
            }
        } else if (q == 3) {
            float b = (bx[col] + bh[col]) * scale;
            unsigned short h = f2bf(b);
            U.s[0] = h;
            U.s[1] = f2bf(b - bf2f(h));
        }
    }
    return U.v8;
}

// x B-frag: q0/q1 -> x (RNE bf16), q2 -> 0, q3 -> {1.0,1.0,0,...}
__device__ __forceinline__ bf16x8 build_xbfrag2(const float* v, int q) {
    union { unsigned u[4]; bf16x8 v8; } U;
#pragma unroll
    for (int p = 0; p < 4; ++p) {
        unsigned val = cvtpk(v[2*p], v[2*p+1]);
        if (q == 2) val = 0u;
        if (q == 3) val = (p == 0) ? 0x3F803F80u : 0u;   // 1.0,1.0 at k=24,25
        U.u[p] = val;
    }
    return U.v8;
}

// activations on PRE-SCALED pre-activations (x' = x*log2e, y' = y*2log2e)
__device__ __forceinline__ float sigmoid2_f(float xp) {
    return __builtin_amdgcn_rcpf(1.0f + __builtin_amdgcn_exp2f(-xp));
}
__device__ __forceinline__ float tanh2_f(float yp) {
    return 1.0f - 2.0f * __builtin_amdgcn_rcpf(1.0f + __builtin_amdgcn_exp2f(yp));
}
__device__ __forceinline__ float leaky_f(float x) {
    return fmaxf(x, NEG_SLOPE * x);   // == LeakyReLU for 0<slope<1
}

__global__ void final_kernel(const float* __restrict__ ws, const float* __restrict__ b2,
                             float* __restrict__ out) {
    int t = threadIdx.x;
    if (t < T_STEPS) out[t] = ws[t * WS_STRIDE] + b2[0];
}

__global__ __launch_bounds__(256, 5) void rgcn_mfma_kernel(
    const float* __restrict__ x,    // [T,N,F]
    const float* __restrict__ h0,   // [N,H]
    const float* __restrict__ Wxz, const float* __restrict__ bxz,
    const float* __restrict__ Whz, const float* __restrict__ bhz,
    const float* __restrict__ Wxr, const float* __restrict__ bxr,
    const float* __restrict__ Whr, const float* __restrict__ bhr,
    const float* __restrict__ Wxh, const float* __restrict__ bxh,
    const float* __restrict__ Whh, const float* __restrict__ bhh,
    const float* __restrict__ W1,  const float* __restrict__ b1,
    const float* __restrict__ W2,
    float* __restrict__ ws,         // [T*WS_STRIDE] accumulators (poison ~ -3e-13, negligible)
    float* __restrict__ out)        // [T] then [N,H]
{
    const int tid  = threadIdx.x;
    const int w    = tid >> 6;       // wave id: owns dims 8w..8w+7
    const int l    = tid & 63;
    const int c    = l & 15;
    const int q    = l >> 4;
    const int base = blockIdx.x * 16;
    const int node = base + c;
    const int d0   = 8 * w + 2 * q;  // lane's two dims: d0, d0+1

    // h exchange: [parity][q][c][wave] uints; a lane's uint4 read IS its B-frag
    __shared__ __align__(16) unsigned hxbuf[2][4][16][4];
    __shared__ __align__(16) unsigned rhbuf[4][16][4];
    // head partials (q-reduced): [t][wave][c], bf16, padded -> 8.7KB
    __shared__ unsigned short pbuf16[T_STEPS][4][17];

    // ---- static A-frags for this wave's 8-dim tile ----
    bf16x8 WHrh, WHrl, WHzh, WHzl, WHhh, WHhl;
    load_wfragW8(Whr, c, q, w, LOG2E,        WHrh, WHrl);
    load_wfragW8(Whz, c, q, w, LOG2E,        WHzh, WHzl);
    load_wfragW8(Whh, c, q, w, 2.0f * LOG2E, WHhh, WHhl);
    bf16x8 WXr = load_xwfragW8(Wxr, bxr, bhr, c, q, w, LOG2E);
    bf16x8 WXz = load_xwfragW8(Wxz, bxz, bhz, c, q, w, LOG2E);
    bf16x8 WXh = load_xwfragW8(Wxh, bxh, bhh, c, q, w, 2.0f * LOG2E);

    // head constants: lane owns dims d0, d0+1
    const float w1a = W1[d0];
    const float w1b = W1[d0 + 1];
    const float b1s = b1[0];
    const float w2l = W2[node];

    // h state: 2 dims per lane
    float hv0, hv1;
    {
        float2 h2 = *(const float2*)(h0 + (size_t)node * H_DIM + d0);
        hv0 = h2.x; hv1 = h2.y;
        hxbuf[0][q][c][w] = cvtpk(hv0, hv1);
    }

    const f32x4 zero4 = {0.0f, 0.0f, 0.0f, 0.0f};

    // x(0) frag -> hoisted x-part accumulators
    f32x4 axr, axz, axh;
    {
        const float4* xp = (const float4*)(x + (size_t)node * F_IN);
        float4 x0 = xp[0], x1 = xp[1];
        float xv[8] = {x0.x, x0.y, x0.z, x0.w, x1.x, x1.y, x1.z, x1.w};
        bf16x8 fx0 = build_xbfrag2(xv, q);
        axr = MFMA(WXr, fx0, zero4);
        axz = MFMA(WXz, fx0, zero4);
        axh = MFMA(WXh, fx0, zero4);
    }

    __syncthreads();     // hxbuf parity 0 visible

#pragma unroll 1
    for (int t = 0; t < T_STEPS; ++t) {
        const int rp = t & 1;          // read parity; write parity = 1-rp

        // issue x(t+1) load now; consumed mid-step (~600cy later)
        int tt = (t + 1 < T_STEPS) ? (t + 1) : (T_STEPS - 1);
        const float4* xp = (const float4*)(x + (size_t)tt * (N_NODES * F_IN)
                                             + (size_t)node * F_IN);
        float4 nx0 = xp[0], nx1 = xp[1];

        // the uint4 read IS the h B-frag (word w' = wave w' packed pair)
        union { uint4 u4; bf16x8 v8; } FH;
        FH.u4 = *(const uint4*)&hxbuf[rp][q][c][0];

        // r (split chains) + z (serial), into hoisted x-parts
        f32x4 arA = MFMA(WHrh, FH.v8, axr);
        f32x4 arB = MFMA(WHrl, FH.v8, zero4);
        f32x4 az  = MFMA(WHzh, FH.v8, axz);
        az        = MFMA(WHzl, FH.v8, az);

        float ar0 = arA[0] + arB[0];
        float ar1 = arA[1] + arB[1];
        float rh0 = sigmoid2_f(ar0) * hv0;
        float rh1 = sigmoid2_f(ar1) * hv1;
        rhbuf[q][c][w] = cvtpk(rh0, rh1);

        // next-x frag build fills the pre-barrier gap
        float nxv[8] = {nx0.x, nx0.y, nx0.z, nx0.w, nx1.x, nx1.y, nx1.z, nx1.w};
        bf16x8 fxn = build_xbfrag2(nxv, q);

        __syncthreads();   // barrier 1: rhbuf ready

        // rh quad read IS the rh B-frag; fill latency with nx-MFMAs + z acts
        union { uint4 u4; bf16x8 v8; } FR;
        FR.u4 = *(const uint4*)&rhbuf[q][c][0];

        f32x4 nxr = MFMA(WXr, fxn, zero4);
        f32x4 nxz = MFMA(WXz, fxn, zero4);
        f32x4 nxh = MFMA(WXh, fxn, zero4);

        float z0 = sigmoid2_f(az[0]);
        float z1 = sigmoid2_f(az[1]);

        f32x4 ahA = MFMA(WHhh, FR.v8, axh);
        f32x4 ahB = MFMA(WHhl, FR.v8, zero4);
        float ah0 = ahA[0] + ahB[0];
        float ah1 = ahA[1] + ahB[1];

        // tanh, blend, head partial over the lane's 2 dims
        float th0 = tanh2_f(ah0);
        float th1 = tanh2_f(ah1);
        float hn0 = th0 + z0 * (hv0 - th0);
        float hn1 = th1 + z1 * (hv1 - th1);
        hv0 = hn0; hv1 = hn1;

        float pnew = fmaf(leaky_f(hn0), w1a, leaky_f(hn1) * w1b);
        pnew += __shfl_xor(pnew, 16);
        pnew += __shfl_xor(pnew, 32);
        if (l < 16) pbuf16[t][w][c] = (unsigned short)cvtpk(pnew, pnew);

        // publish packed h(t+1)
        hxbuf[1 - rp][q][c][w] = cvtpk(hn0, hn1);

        axr = nxr; axz = nxz; axh = nxh;

        __syncthreads();   // barrier 2: h(t+1) exchange + rhbuf reuse fence
    }

    // ---- post-loop head reduction: each wave handles 16 t's ----
#pragma unroll
    for (int rep = 0; rep < 4; ++rep) {
        int t = w * 16 + rep * 4 + q;
        float s = 0.0f;
#pragma unroll
        for (int g = 0; g < 4; ++g) s += bf2f(pbuf16[t][g][c]);
        float a2 = leaky_f(s + b1s) * w2l;
        a2 += __shfl_xor(a2, 1); a2 += __shfl_xor(a2, 2);
        a2 += __shfl_xor(a2, 4); a2 += __shfl_xor(a2, 8);
        if (c == 0) atomicAdd(&ws[t * WS_STRIDE], a2);
    }

    // h_fin: lane stores its 2 contiguous dims (coalesced across q,w)
    *(float2*)(out + T_STEPS + (size_t)node * H_DIM + d0) = (float2){hv0, hv1};
}

extern "C" void kernel_launch(void* const* d_in, const int* in_sizes, int n_in,
                              void* d_out, int out_size, void* d_ws, size_t ws_size,
                              hipStream_t stream) {
    const float* x    = (const float*)d_in[0];
    // d_in[1] edge_index (int64), d_in[2] edge_weight: dead for K=1 ChebConv
    const float* h0   = (const float*)d_in[3];
    const float* Wxz  = (const float*)d_in[4];
    const float* bxz  = (const float*)d_in[5];
    const float* Whz  = (const float*)d_in[6];
    const float* bhz  = (const float*)d_in[7];
    const float* Wxr  = (const float*)d_in[8];
    const float* bxr  = (const float*)d_in[9];
    const float* Whr  = (const float*)d_in[10];
    const float* bhr  = (const float*)d_in[11];
    const float* Wxh  = (const float*)d_in[12];
    const float* bxh  = (const float*)d_in[13];
    const float* Whh  = (const float*)d_in[14];
    const float* bhh  = (const float*)d_in[15];
    const float* W1   = (const float*)d_in[16];
    const float* b1   = (const float*)d_in[17];
    const float* W2   = (const float*)d_in[18];
    const float* b2   = (const float*)d_in[19];
    float* out = (float*)d_out;
    float* ws  = (float*)d_ws;

    const int grid = N_NODES / 16;  // 1250 blocks x 4 waves = 5000 waves
    rgcn_mfma_kernel<<<grid, 256, 0, stream>>>(
        x, h0, Wxz, bxz, Whz, bhz, Wxr, bxr, Whr, bhr,
        Wxh, bxh, Whh, bhh, W1, b1, W2, ws, out);

    final_kernel<<<1, 64, 0, stream>>>(ws, b2, out);
}

// Round 13
// 179.199 us; speedup vs baseline: 1.1006x; 1.0592x over previous
//
#include <hip/hip_runtime.h>
#include <hip/hip_bf16.h>

// T=64, N=20000, F=8, H=32. edge_index/edge_weight dead (K=1 ChebConv).
// R22 = R18 (best, 85us) with ALL in-loop global memory ELIMINATED.
// Falsification chain: R19 (ILP split) lost, R20 (2-stream ILP) lost,
// R21 (4-wave TLP, 4.88 waves/SIMD) lost with VALUBusy STILL ~54% -->
// the stall is synchronized across independent blocks. Culprit: the
// __syncthreads() vmcnt(0) drain. Every step issues an x global load a
// few hundred cy before a barrier; the barrier drains it to completion
// (HBM ~900cy / L2 ~200cy), stalling the whole block EVERY step. This is
// the invariant ~1.5us/step wall of R14-R21, and why R16's barrier
// removal was the biggest single win.
// Fix: preload the block's whole x slab (64t x 16n x 8f = 32KB f32) as
// RNE bf16 into 16KB LDS once (coalesced, ~7us machine-wide, same total
// HBM bytes); the t-loop is then pure LDS+VALU+MFMA -- x B-frag is one
// broadcast ds_read_b128 + 1 cndmask (q3 bias-ones word; q2/garbage
// words are nulled by A-side zeros). vmcnt drains become no-ops.
// Residency: pbuf shrunk via in-loop q-reduce (2 shfl_xor, symmetric,
// R21-validated) to [64][2][17] bf16 = 4.4KB. LDS ~21.8KB -> 7 blk/CU,
// all 1250 blocks in one round.
// Numerics: identical RNE conversions; head has FEWER bf16 roundings
// (2 vs 8 per node-t) -> absmax <= 0.009 (threshold 0.0199).
#define T_STEPS 64
#define N_NODES 20000
#define F_IN    8
#define H_DIM   32
#define NEG_SLOPE 0.01f
#define WS_STRIDE 32   // floats; one 128B cacheline per t
#define LOG2E 1.44269504f

typedef __attribute__((ext_vector_type(8))) short bf16x8;
typedef __attribute__((ext_vector_type(4))) float f32x4;

#define MFMA(a, b, c) __builtin_amdgcn_mfma_f32_16x16x32_bf16((a), (b), (c), 0, 0, 0)

// ---------- RNE helpers (cold path: weight/frag setup only) ----------
__device__ __forceinline__ unsigned short f2bf(float f) {
    unsigned u = __float_as_uint(f);
    u += 0x7FFFu + ((u >> 16) & 1u);          // RNE
    return (unsigned short)(u >> 16);
}
__device__ __forceinline__ float bf2f(unsigned short s) {
    return __uint_as_float(((unsigned)s) << 16);
}
__device__ __forceinline__ void split_pack8_rne(const float* v, bf16x8& hi, bf16x8& lo) {
    union { unsigned u[4]; bf16x8 v8; } H, L;
#pragma unroll
    for (int p = 0; p < 4; ++p) {
        float a = v[2*p], b = v[2*p+1];
        unsigned short ha = f2bf(a), hb = f2bf(b);
        unsigned short la = f2bf(a - bf2f(ha)), lb = f2bf(b - bf2f(hb));
        H.u[p] = (unsigned)ha | ((unsigned)hb << 16);
        L.u[p] = (unsigned)la | ((unsigned)lb << 16);
    }
    hi = H.v8; lo = L.v8;
}

// ---------- hot-path pack: HW v_cvt_pk_bf16_f32 via standard casts ----------
__device__ __forceinline__ unsigned cvtpk(float a, float b) {
    union { __hip_bfloat162 h; unsigned u; } U;
    U.h = __float22bfloat162_rn(float2{a, b});   // lo16 = bf(a), hi16 = bf(b)
    return U.u;
}

// Wave-relative K-permutation: k-slot (q, j) -> h-dim
//   j<4  -> Rown + 4q + j      (own dims; B-frag words u[0],u[1])
//   j>=4 -> Roth + 4q + (j-4)  (peer dims; B-frag words u[2],u[3])
// Applied to BOTH A and B frags, so each gate's C-layout == next B layout,
// and the peer's packed own-half IS our u[2],u[3].

// A-frag of W^T for output tile Rout, K in wave-relative sigma order,
// pre-scaled (log2e folds the exp base change into static data).
__device__ __forceinline__ void load_wfragW(const float* __restrict__ W, int c, int q,
                                            int Rout, int Rown, int Roth, float scale,
                                            bf16x8& hi, bf16x8& lo) {
    float v[8];
#pragma unroll
    for (int j = 0; j < 8; ++j) {
        int dim = (j < 4) ? (Rown + 4*q + j) : (Roth + 4*q + (j - 4));
        v[j] = W[dim * H_DIM + (Rout + c)] * scale;
    }
    split_pack8_rne(v, hi, lo);
}

// Combined x-weight + bias A-frag for tile Rout (K-slot plan, k = 8q+j):
//   q=0: W_hi[j]   q=1: W_lo[j]   q=2: 0   q=3: j==0 bias_hi, j==1 bias_lo
// pairs with x B-frag (q0: x_rne, q1: x_rne, q2: garbage-x (A=0),
// q3: word0 {1,1}, rest garbage-x (A=0)) ->
//   x*(W_hi+W_lo) + bias  (weight full precision, x single RNE bf16).
__device__ __forceinline__ bf16x8 load_xwfragW(const float* __restrict__ Wx,
                                               const float* __restrict__ bx,
                                               const float* __restrict__ bh,
                                               int c, int q, int Rout, float scale) {
    union { unsigned short s[8]; bf16x8 v8; } U;
#pragma unroll
    for (int j = 0; j < 8; ++j) U.s[j] = 0;
    if (q == 0) {
#pragma unroll
        for (int j = 0; j < 8; ++j) U.s[j] = f2bf(Wx[j * H_DIM + Rout + c] * scale);
    } else if (q == 1) {
#pragma unroll
        for (int j = 0; j < 8; ++j) {
            float w0 = Wx[j * H_DIM + Rout + c] * scale;
            unsigned short h = f2bf(w0);
            U.s[j] = f2bf(w0 - bf2f(h));
        }
    } else if (q == 3) {
        float b = (bx[Rout + c] + bh[Rout + c]) * scale;
        unsigned short h = f2bf(b);
        U.s[0] = h;
        U.s[1] = f2bf(b - bf2f(h));
    }
    return U.v8;
}

// full B-frag from packed own + packed peer halves
__device__ __forceinline__ bf16x8 frag4(unsigned o01, unsigned o23,
                                        unsigned p01, unsigned p23) {
    union { unsigned u[4]; bf16x8 v8; } U;
    U.u[0] = o01; U.u[1] = o23; U.u[2] = p01; U.u[3] = p23;
    return U.v8;
}

// activations on PRE-SCALED pre-activations (x' = x*log2e, y' = y*2log2e):
// sigmoid(x) = rcp(1 + 2^(-x')), tanh(y) = 1 - 2*rcp(1 + 2^(y'))
__device__ __forceinline__ float sigmoid2_f(float xp) {
    return __builtin_amdgcn_rcpf(1.0f + __builtin_amdgcn_exp2f(-xp));
}
__device__ __forceinline__ float tanh2_f(float yp) {
    return 1.0f - 2.0f * __builtin_amdgcn_rcpf(1.0f + __builtin_amdgcn_exp2f(yp));
}
__device__ __forceinline__ float leaky_f(float x) {
    return fmaxf(x, NEG_SLOPE * x);   // == LeakyReLU for 0<slope<1
}

__global__ void final_kernel(const float* __restrict__ ws, const float* __restrict__ b2,
                             float* __restrict__ out) {
    int t = threadIdx.x;
    if (t < T_STEPS) out[t] = ws[t * WS_STRIDE] + b2[0];
}

__global__ __launch_bounds__(128, 3) void rgcn_mfma_kernel(
    const float* __restrict__ x,    // [T,N,F]
    const float* __restrict__ h0,   // [N,H]
    const float* __restrict__ Wxz, const float* __restrict__ bxz,
    const float* __restrict__ Whz, const float* __restrict__ bhz,
    const float* __restrict__ Wxr, const float* __restrict__ bxr,
    const float* __restrict__ Whr, const float* __restrict__ bhr,
    const float* __restrict__ Wxh, const float* __restrict__ bxh,
    const float* __restrict__ Whh, const float* __restrict__ bhh,
    const float* __restrict__ W1,  const float* __restrict__ b1,
    const float* __restrict__ W2,
    float* __restrict__ ws,         // [T*WS_STRIDE] accumulators (poison ~ -3e-13, negligible)
    float* __restrict__ out)        // [T] then [N,H]
{
    const int tid  = threadIdx.x;
    const int w    = tid >> 6;       // wave id: owns dim-tile Rown
    const int l    = tid & 63;
    const int c    = l & 15;
    const int q    = l >> 4;
    const int base = blockIdx.x * 16;
    const int node = base + c;
    const int Rown = 16 * w;
    const int Roth = 16 - Rown;

    // x slab, RNE bf16: [t][node c][4 words of 2 bf16] = 16KB, read-only after preload
    __shared__ __align__(16) unsigned xbuf[T_STEPS][16][4];
    // PACKED bf16 exchanges (uint2 per lane): h parity-double-buffered, rh single
    __shared__ __align__(8) uint2 hxbuf[2][2][4][16];   // [parity][wave][q][c]
    __shared__ __align__(8) uint2 rhbuf[2][4][16];      // [wave][q][c]
    // head partials, q-reduced in-loop: [t][wave][c] bf16 = 4.4KB
    __shared__ unsigned short pbuf16[T_STEPS][2][17];

    // ---- static A-frags, wave-relative sigma K, pre-scaled ----
    bf16x8 WHrh, WHrl, WHzh, WHzl, WHhh, WHhl;
    load_wfragW(Whr, c, q, Rown, Rown, Roth, LOG2E,        WHrh, WHrl);
    load_wfragW(Whz, c, q, Rown, Rown, Roth, LOG2E,        WHzh, WHzl);
    load_wfragW(Whh, c, q, Rown, Rown, Roth, 2.0f * LOG2E, WHhh, WHhl);
    bf16x8 WXr = load_xwfragW(Wxr, bxr, bhr, c, q, Rown, LOG2E);
    bf16x8 WXz = load_xwfragW(Wxz, bxz, bhz, c, q, Rown, LOG2E);
    bf16x8 WXh = load_xwfragW(Wxh, bxh, bhh, c, q, Rown, 2.0f * LOG2E);

    // head constants: lane owns dims Rown+4q+i
    float w1v[4];
#pragma unroll
    for (int i = 0; i < 4; ++i) w1v[i] = W1[Rown + 4*q + i];
    const float b1s = b1[0];
    const float w2l = W2[node];

    // h state: own 4 dims (f32) + pre-packed own bf16 pair
    float hv[4];
    unsigned own01, own23;
    {
        float4 h4 = ((const float4*)(h0 + (size_t)node * H_DIM + Rown))[q];
        hv[0] = h4.x; hv[1] = h4.y; hv[2] = h4.z; hv[3] = h4.w;
        own01 = cvtpk(hv[0], hv[1]);
        own23 = cvtpk(hv[2], hv[3]);
        hxbuf[0][w][q][c] = uint2{own01, own23};   // parity 0 = step 0
    }

    // ---- x slab preload: 2048 half-cells, coalesced 512B runs, RNE bf16 ----
    // idx = it*128+tid; t = idx>>5; cell = (idx>>1)&15; half = idx&1
#pragma unroll
    for (int it = 0; it < 16; ++it) {
        int idx = it * 128 + tid;
        int t   = idx >> 5;
        int ce  = (idx >> 1) & 15;
        int hf  = idx & 1;
        const float4 v = *(const float4*)(
            x + ((size_t)t * N_NODES + base + ce) * F_IN + hf * 4);
        xbuf[t][ce][hf * 2]     = cvtpk(v.x, v.y);
        xbuf[t][ce][hf * 2 + 1] = cvtpk(v.z, v.w);
    }

    const f32x4 zero4 = {0.0f, 0.0f, 0.0f, 0.0f};
    const unsigned ONES2 = 0x3F803F80u;   // {1.0bf16, 1.0bf16} for q3 word0
    const bool q3 = (q == 3);

    __syncthreads();     // xbuf + hxbuf parity 0 ready (last vmcnt drain)

    // x(0) B-frag from LDS -> hoisted x-part accumulators
    f32x4 axr, axz, axh;
    {
        union { uint4 u4; } X; X.u4 = *(const uint4*)&xbuf[0][c][0];
        bf16x8 fx0 = frag4(q3 ? ONES2 : X.u4.x, X.u4.y, X.u4.z, X.u4.w);
        axr = MFMA(WXr, fx0, zero4);
        axz = MFMA(WXz, fx0, zero4);
        axh = MFMA(WXh, fx0, zero4);
    }

#pragma unroll 1
    for (int t = 0; t < T_STEPS; ++t) {
        const int rp = t & 1;          // read parity; write parity = 1-rp

        // peer packed h (8B LDS read; only memory op before barrier 1)
        uint2 ohp = hxbuf[rp][1 - w][q][c];
        bf16x8 fh = frag4(own01, own23, ohp.x, ohp.y);

        // r (split chains) + z (serial), into hoisted x-parts
        f32x4 arA = MFMA(WHrh, fh, axr);
        f32x4 arB = MFMA(WHrl, fh, zero4);
        f32x4 az  = MFMA(WHzh, fh, axz);
        az        = MFMA(WHzl, fh, az);
        f32x4 ar  = arA + arB;

        // r gate + r*h own 4 dims; pack once, publish packed
        float rh4[4];
#pragma unroll
        for (int i = 0; i < 4; ++i) rh4[i] = sigmoid2_f(ar[i]) * hv[i];
        unsigned rh01 = cvtpk(rh4[0], rh4[1]);
        unsigned rh23 = cvtpk(rh4[2], rh4[3]);
        rhbuf[w][q][c] = uint2{rh01, rh23};

        __syncthreads();   // barrier 1: rhbuf ready (no global loads to drain)

        // x(t+1) B-frag from LDS + hoisted nx-MFMAs fill the rh read latency
        int tt = (t + 1 < T_STEPS) ? (t + 1) : (T_STEPS - 1);
        union { uint4 u4; } X; X.u4 = *(const uint4*)&xbuf[tt][c][0];
        uint2 orh = rhbuf[1 - w][q][c];

        bf16x8 fxn = frag4(q3 ? ONES2 : X.u4.x, X.u4.y, X.u4.z, X.u4.w);
        f32x4 nxr = MFMA(WXr, fxn, zero4);
        f32x4 nxz = MFMA(WXz, fxn, zero4);
        f32x4 nxh = MFMA(WXh, fxn, zero4);

        float zv[4];
#pragma unroll
        for (int i = 0; i < 4; ++i) zv[i] = sigmoid2_f(az[i]);

        bf16x8 fr = frag4(rh01, rh23, orh.x, orh.y);
        f32x4 ahA = MFMA(WHhh, fr, axh);
        f32x4 ahB = MFMA(WHhl, fr, zero4);
        f32x4 ah  = ahA + ahB;

        // tanh, blend (th + z*(hv-th)), head partial over own 4 dims
        float pnew = 0.0f;
#pragma unroll
        for (int i = 0; i < 4; ++i) {
            float th = tanh2_f(ah[i]);
            float hn = th + zv[i] * (hv[i] - th);
            hv[i] = hn;
            pnew = fmaf(leaky_f(hn), w1v[i], pnew);
        }
        // q-reduce (f32, exact) then ONE bf16 write per (wave, node)
        pnew += __shfl_xor(pnew, 16);
        pnew += __shfl_xor(pnew, 32);
        if (l < 16) pbuf16[t][w][c] = (unsigned short)cvtpk(pnew, pnew);

        // pack h(t+1) once; publish packed
        own01 = cvtpk(hv[0], hv[1]);
        own23 = cvtpk(hv[2], hv[3]);
        hxbuf[1 - rp][w][q][c] = uint2{own01, own23};

        axr = nxr; axz = nxz; axh = nxh;

        __syncthreads();   // barrier 2: h(t+1) exchange + rhbuf reuse fence
    }

    // ---- post-loop head reduction: each wave handles 32 t's ----
#pragma unroll
    for (int rep = 0; rep < 8; ++rep) {
        int t = w * 32 + rep * 4 + q;
        float s = bf2f(pbuf16[t][0][c]) + bf2f(pbuf16[t][1][c]);
        float a2 = leaky_f(s + b1s) * w2l;
        a2 += __shfl_xor(a2, 1); a2 += __shfl_xor(a2, 2);
        a2 += __shfl_xor(a2, 4); a2 += __shfl_xor(a2, 8);
        if (c == 0) atomicAdd(&ws[t * WS_STRIDE], a2);
    }

    // h_fin: each wave stores its own dim-tile, contiguous float4 per lane
    *(float4*)(out + T_STEPS + (size_t)node * H_DIM + Rown + 4*q) =
        (float4){hv[0], hv[1], hv[2], hv[3]};
}

extern "C" void kernel_launch(void* const* d_in, const int* in_sizes, int n_in,
                              void* d_out, int out_size, void* d_ws, size_t ws_size,
                              hipStream_t stream) {
    const float* x    = (const float*)d_in[0];
    // d_in[1] edge_index (int64), d_in[2] edge_weight: dead for K=1 ChebConv
    const float* h0   = (const float*)d_in[3];
    const float* Wxz  = (const float*)d_in[4];
    const float* bxz  = (const float*)d_in[5];
    const float* Whz  = (const float*)d_in[6];
    const float* bhz  = (const float*)d_in[7];
    const float* Wxr  = (const float*)d_in[8];
    const float* bxr  = (const float*)d_in[9];
    const float* Whr  = (const float*)d_in[10];
    const float* bhr  = (const float*)d_in[11];
    const float* Wxh  = (const float*)d_in[12];
    const float* bxh  = (const float*)d_in[13];
    const float* Whh  = (const float*)d_in[14];
    const float* bhh  = (const float*)d_in[15];
    const float* W1   = (const float*)d_in[16];
    const float* b1   = (const float*)d_in[17];
    const float* W2   = (const float*)d_in[18];
    const float* b2   = (const float*)d_in[19];
    float* out = (float*)d_out;
    float* ws  = (float*)d_ws;

    const int grid = N_NODES / 16;  // 1250 blocks x 2 waves = 2500 waves
    rgcn_mfma_kernel<<<grid, 128, 0, stream>>>(
        x, h0, Wxz, bxz, Whz, bhz, Wxr, bxr, Whr, bhr,
        Wxh, bxh, Whh, bhh, W1, b1, W2, ws, out);

    final_kernel<<<1, 64, 0, stream>>>(ws, b2, out);
}